// Round 11
// baseline (1341.224 us; speedup 1.0000x reference)
//
#include <hip/hip_runtime.h>
#include <cmath>

#define BATCH 32
#define SEQ   2048
#define EMB   512
#define NOUT  256
#define PS    16
#define KW    16
#define JTOT  8192  // K*E flat contraction length, j = k*512 + i (i fastest)
#define KCL   288   // Eigen threaded gebp kc (linear dot: 512 = 288 + 224)

// GEMM tiling for k_conv: M=bn (8192), N=o (512), K=j (8192)
#define MT 128      // bn-tile
#define NT 128      // o-tile
#define KS 32       // j-tile; 288 = 9*KS, tail 128 = 4*KS -> panel folds align

// XLA EmitFastTanh / Eigen ptanh_float: rational approx, f32, FMA Horner.
__device__ __forceinline__ float xla_tanhf(float x) {
#pragma clang fp contract(off)
    float ax = fabsf(x);
    float xc = x;
    if (xc < -7.90531110763549805f) xc = -7.90531110763549805f;
    if (xc >  7.90531110763549805f) xc =  7.90531110763549805f;
    float x2 = xc * xc;
    float p = __builtin_fmaf(x2, -2.76076847742355e-16f, 2.00018790482477e-13f);
    p = __builtin_fmaf(x2, p, -8.60467152213735e-11f);
    p = __builtin_fmaf(x2, p,  5.12229709037114e-08f);
    p = __builtin_fmaf(x2, p,  1.48572235717979e-05f);
    p = __builtin_fmaf(x2, p,  6.37261928875436e-04f);
    p = __builtin_fmaf(x2, p,  4.89352455891786e-03f);
    float num = xc * p;
    float q = __builtin_fmaf(x2, 1.19825839466702e-06f, 1.18534705686654e-04f);
    q = __builtin_fmaf(x2, q, 2.26843463243900e-03f);
    q = __builtin_fmaf(x2, q, 4.89352518554385e-03f);
    float r = num / q;
    return (ax < 0.0004f) ? x : r;
}

// K1: wT[j][o] = conv_w[o][i][k],  j = k*512 + i  (XLA/Eigen im2col order)
__global__ __launch_bounds__(256) void k_transpose_w(const float* __restrict__ w,
                                                     float* __restrict__ wT) {
    int t = blockIdx.x * 256 + threadIdx.x;   // t = j*512 + o
    int o = t & 511;
    int i = (t >> 9) & 511;
    int k = t >> 18;
    wT[t] = w[(size_t)o * 8192 + i * 16 + k];
}

// K2: conv1d as double-buffered LDS-tiled f32 GEMM, bit-exact Eigen gebp
// accumulation. Per output (bn,o): panels of kc=288 over j (k-major, i-minor),
// each panel one sequential fmaf chain (pk), panels left-folded into ys in
// order. KS=32 divides 288 (9 tiles) and the tail 128 (4 tiles) so folds only
// happen at tile boundaries (js%9==8, js==255). Tile 128x128, 256 threads,
// 8x8 micro-tile (fragments split m,o into {t*4, 64+t*4} to keep LDS reads
// 2-way only). Reg-staged double buffer: issue next tile's global loads before
// compute, write LDS after the post-compute barrier.
__global__ __launch_bounds__(256) void k_conv(const float* __restrict__ x,
                                              const float* __restrict__ wT,
                                              const float* __restrict__ cb,
                                              float* __restrict__ y) {
#pragma clang fp contract(off)
    __shared__ __align__(16) float sA[2][KS][MT + 4];   // [buf][kk][m]
    __shared__ __align__(16) float sB[2][KS][NT];       // [buf][kk][o']

    int bn0 = blockIdx.x << 7;     // 0..63 -> bn tile base
    int b   = bn0 >> 8;
    int n0  = bn0 & 255;           // 0 or 128
    int o0  = blockIdx.y << 7;     // 0..3

    int tid = threadIdx.x;
    int tm  = tid & 15;            // micro m-group
    int tn  = tid >> 4;            // micro o-group

    // staging maps
    int ma  = tid & 127;           // A: m row (0..127)
    int kkq = tid >> 7;            // A: kk half (0/1)

    float ys[8][8], pk[8][8];
#pragma unroll
    for (int mi = 0; mi < 8; ++mi)
#pragma unroll
        for (int ni = 0; ni < 8; ++ni) { ys[mi][ni] = 0.0f; pk[mi][ni] = 0.0f; }

    const float* xb = x + (size_t)b * SEQ * EMB;

    float4 ra[4], rb[4];

#define LOAD_T(js_)                                                            \
    {                                                                          \
        int k_  = (js_) >> 4;                                                  \
        int i0_ = ((js_) & 15) << 5;                                           \
        int s_  = ((n0 + ma) << 3) - 4 + k_;                                   \
        _Pragma("unroll")                                                      \
        for (int r = 0; r < 4; ++r) {                                          \
            int kk0 = (kkq << 4) + (r << 2);                                   \
            ra[r] = make_float4(0.f, 0.f, 0.f, 0.f);                           \
            if (s_ >= 0 && s_ < SEQ)                                           \
                ra[r] = *(const float4*)(xb + ((size_t)s_ << 9) + i0_ + kk0);  \
        }                                                                      \
        const float* wrow_ = wT + (((size_t)(js_) << 5) << 9) + o0;            \
        _Pragma("unroll")                                                      \
        for (int r = 0; r < 4; ++r) {                                          \
            int e  = (tid + (r << 8)) << 2;                                    \
            int kk = e >> 7;                                                   \
            int o4 = e & 127;                                                  \
            rb[r] = *(const float4*)(wrow_ + ((size_t)kk << 9) + o4);          \
        }                                                                      \
    }

#define WRITE_T(bf_)                                                           \
    {                                                                          \
        _Pragma("unroll")                                                      \
        for (int r = 0; r < 4; ++r) {                                          \
            int kk0 = (kkq << 4) + (r << 2);                                   \
            sA[bf_][kk0 + 0][ma] = ra[r].x;                                    \
            sA[bf_][kk0 + 1][ma] = ra[r].y;                                    \
            sA[bf_][kk0 + 2][ma] = ra[r].z;                                    \
            sA[bf_][kk0 + 3][ma] = ra[r].w;                                    \
        }                                                                      \
        _Pragma("unroll")                                                      \
        for (int r = 0; r < 4; ++r) {                                          \
            int e  = (tid + (r << 8)) << 2;                                    \
            int kk = e >> 7;                                                   \
            int o4 = e & 127;                                                  \
            *(float4*)&sB[bf_][kk][o4] = rb[r];                                \
        }                                                                      \
    }

    // prologue: stage js=0 into buffer 0
    LOAD_T(0);
    WRITE_T(0);
    __syncthreads();

    for (int js = 0; js < 256; ++js) {
        int cur = js & 1;
        if (js < 255) LOAD_T(js + 1);          // issue early; lands during compute

        // micro-kernel: pk chains ascend in kk (exact Eigen panel order)
#pragma unroll
        for (int kk = 0; kk < KS; ++kk) {
            float4 a0 = *(const float4*)&sA[cur][kk][tm << 2];
            float4 a1 = *(const float4*)&sA[cur][kk][64 + (tm << 2)];
            float4 b0 = *(const float4*)&sB[cur][kk][tn << 2];
            float4 b1 = *(const float4*)&sB[cur][kk][64 + (tn << 2)];
            float av[8] = {a0.x, a0.y, a0.z, a0.w, a1.x, a1.y, a1.z, a1.w};
            float bv[8] = {b0.x, b0.y, b0.z, b0.w, b1.x, b1.y, b1.z, b1.w};
#pragma unroll
            for (int mi = 0; mi < 8; ++mi)
#pragma unroll
                for (int ni = 0; ni < 8; ++ni)
                    pk[mi][ni] = __builtin_fmaf(av[mi], bv[ni], pk[mi][ni]);
        }
        // panel left-fold (ys += pk) at kc=288 boundaries and the 128 tail
        if ((js % 9) == 8 || js == 255) {
#pragma unroll
            for (int mi = 0; mi < 8; ++mi)
#pragma unroll
                for (int ni = 0; ni < 8; ++ni) {
                    ys[mi][ni] = ys[mi][ni] + pk[mi][ni];
                    pk[mi][ni] = 0.0f;
                }
        }
        __syncthreads();                        // all waves done reading buf cur
        if (js < 255) {
            WRITE_T(cur ^ 1);
            __syncthreads();                    // buf cur^1 ready for next js
        }
    }

    // epilogue: bias add (exact r9/r10 order) + store
#pragma unroll
    for (int mi = 0; mi < 8; ++mi) {
        int m = (mi < 4) ? ((tm << 2) + mi) : (64 + (tm << 2) + mi - 4);
        int n = n0 + m;
        float* dst = y + (((size_t)(b << 8) + n) << 9) + o0;
#pragma unroll
        for (int ni = 0; ni < 8; ++ni) {
            int oo = (ni < 4) ? ((tn << 2) + ni) : (64 + (tn << 2) + ni - 4);
            dst[oo] = ys[mi][ni] + cb[o0 + oo];
        }
    }
#undef LOAD_T
#undef WRITE_T
}

// K3: per (b,n): off = relu(y) @ lin_w.T + lin_b with Eigen kc=288 panel split
// (512 = 288 + 224), then decode op-for-op in f32 (contract off), XLA tanh,
// jax-f32 linspace t (t = p * f32(1/15)).
__global__ __launch_bounds__(256) void k_decode(const float* __restrict__ y,
                                               const float* __restrict__ lw,
                                               const float* __restrict__ lb,
                                               const float* __restrict__ wb,
                                               int* __restrict__ idx) {
#pragma clang fp contract(off)
    int bn = blockIdx.x * 256 + threadIdx.x;   // 0..8191
    if (bn >= BATCH * NOUT) return;
    const float* yy = y + ((size_t)bn << 9);

    float s0, s1;
    {
        float p0 = 0.0f, p1 = 0.0f;
        for (int e = 0; e < KCL; ++e) {
            float v = yy[e];
            float r = v > 0.0f ? v : 0.0f;
            p0 = __builtin_fmaf(r, lw[e],       p0);
            p1 = __builtin_fmaf(r, lw[EMB + e], p1);
        }
        s0 = p0; s1 = p1;                  // panel 0 stores (beta=0)
    }
    {
        float p0 = 0.0f, p1 = 0.0f;
        for (int e = KCL; e < EMB; ++e) {
            float v = yy[e];
            float r = v > 0.0f ? v : 0.0f;
            p0 = __builtin_fmaf(r, lw[e],       p0);
            p1 = __builtin_fmaf(r, lw[EMB + e], p1);
        }
        s0 = s0 + p0; s1 = s1 + p1;        // panel 1 accumulates
    }
    float off0 = s0 + lb[0];
    float off1 = s1 + lb[1];

    int n = bn & (NOUT - 1);
    float anchor = (0.5f + (float)n) / 256.0f;        // exact in f32
    float dx  = xla_tanhf(off0) * 0.00390625f;        // * poi (2^-8, exact)
    float a1  = off1 + wb[0];
    float tww = xla_tanhf(a1);
    float rwv = tww > 0.0f ? tww : 0.0f;
    float dwv = rwv * 0.00390625f;
    float adx = anchor + dx;                          // left-assoc like jnp
    float x0 = adx - dwv; x0 = x0 < 0.0f ? 0.0f : (x0 > 1.0f ? 1.0f : x0);
    float x1 = adx + dwv; x1 = x1 < 0.0f ? 0.0f : (x1 > 1.0f ? 1.0f : x1);

    const float delta = 1.0f / 15.0f;                 // f32 0.06666667
#pragma unroll
    for (int p = 0; p < PS; ++p) {
        float t  = (float)p * delta;                  // jax linspace: iota*delta, f32
        float om = 1.0f - t;
        float gs = x0 * om + x1 * t;                  // mul,mul,add — contract off
        float gxn = 2.0f * gs - 1.0f;
        float gp1 = gxn + 1.0f;
        float ixx = (gp1 * 2048.0f - 1.0f) * 0.5f;
        float rr = rintf(ixx);                        // round half-even
        int id = (int)rr;
        id = id < 0 ? 0 : (id > SEQ - 1 ? SEQ - 1 : id);
        idx[bn * PS + p] = id;
    }
}

// K4: out[b][n][p][:] = x[b][idx[b,n,p]][:]   (exact f32 row copy, 2048 B)
__global__ __launch_bounds__(128) void k_gather(const float* __restrict__ x,
                                                const int* __restrict__ idx,
                                                float* __restrict__ out) {
    int g = blockIdx.x;                 // (b*256+n)*16+p, 131072 blocks
    int b = g >> 12;
    int sidx = idx[g];
    const float4* src = (const float4*)(x + (((size_t)b * SEQ + sidx) << 9));
    float4* dst = (float4*)(out + ((size_t)g << 9));
    dst[threadIdx.x] = src[threadIdx.x];
}

extern "C" void kernel_launch(void* const* d_in, const int* in_sizes, int n_in,
                              void* d_out, int out_size, void* d_ws, size_t ws_size,
                              hipStream_t stream) {
    const float* x      = (const float*)d_in[0];
    const float* conv_w = (const float*)d_in[1];
    const float* conv_b = (const float*)d_in[2];
    const float* lin_w  = (const float*)d_in[3];
    const float* lin_b  = (const float*)d_in[4];
    const float* wbias  = (const float*)d_in[5];
    float* out = (float*)d_out;

    // Scratch inside d_out (268 MB f32): wT [0,16.8MB), y [16.8,33.6MB).
    // Both consumed by k_decode before k_gather overwrites d_out.
    // idx (512 KB) in d_ws.
    float* wT  = (float*)d_out;
    float* y   = (float*)((char*)d_out + (size_t)16777216);
    int*   idx = (int*)d_ws;

    hipLaunchKernelGGL(k_transpose_w, dim3(16384), dim3(256), 0, stream, conv_w, wT);
    hipLaunchKernelGGL(k_conv,        dim3(64, 4), dim3(256), 0, stream, x, wT, conv_b, y);
    hipLaunchKernelGGL(k_decode,      dim3(32),    dim3(256), 0, stream, y, lin_w, lin_b, wbias, idx);
    hipLaunchKernelGGL(k_gather,      dim3(BATCH * NOUT * PS), dim3(128), 0, stream, x, idx, out);
}

// Round 12
// 1082.302 us; speedup vs baseline: 1.2392x; 1.2392x over previous
//
#include <hip/hip_runtime.h>
#include <cmath>

#define BATCH 32
#define SEQ   2048
#define EMB   512
#define NOUT  256
#define PS    16
#define KW    16
#define JTOT  8192  // K*E flat contraction length, j = k*512 + i (i fastest)
#define KCL   288   // Eigen threaded gebp kc (linear dot: 512 = 288 + 224)

// GEMM tiling for k_conv: M=bn (8192), N=o (512), K=j (8192)
#define MB 64       // bn-tile
#define NB 128      // o-tile
#define KS 32       // j-tile; 288 = 9*KS, tail 128 = 4*KS -> panel folds align

// XLA EmitFastTanh / Eigen ptanh_float: rational approx, f32, FMA Horner.
__device__ __forceinline__ float xla_tanhf(float x) {
#pragma clang fp contract(off)
    float ax = fabsf(x);
    float xc = x;
    if (xc < -7.90531110763549805f) xc = -7.90531110763549805f;
    if (xc >  7.90531110763549805f) xc =  7.90531110763549805f;
    float x2 = xc * xc;
    float p = __builtin_fmaf(x2, -2.76076847742355e-16f, 2.00018790482477e-13f);
    p = __builtin_fmaf(x2, p, -8.60467152213735e-11f);
    p = __builtin_fmaf(x2, p,  5.12229709037114e-08f);
    p = __builtin_fmaf(x2, p,  1.48572235717979e-05f);
    p = __builtin_fmaf(x2, p,  6.37261928875436e-04f);
    p = __builtin_fmaf(x2, p,  4.89352455891786e-03f);
    float num = xc * p;
    float q = __builtin_fmaf(x2, 1.19825839466702e-06f, 1.18534705686654e-04f);
    q = __builtin_fmaf(x2, q, 2.26843463243900e-03f);
    q = __builtin_fmaf(x2, q, 4.89352518554385e-03f);
    float r = num / q;
    return (ax < 0.0004f) ? x : r;
}

// K1: wT[j][o] = conv_w[o][i][k],  j = k*512 + i  (XLA/Eigen im2col order)
__global__ __launch_bounds__(256) void k_transpose_w(const float* __restrict__ w,
                                                     float* __restrict__ wT) {
    int t = blockIdx.x * 256 + threadIdx.x;   // t = j*512 + o
    int o = t & 511;
    int i = (t >> 9) & 511;
    int k = t >> 18;
    wT[t] = w[(size_t)o * 8192 + i * 16 + k];
}

// K2: conv1d as LDS-tiled f32 GEMM, bit-exact Eigen gebp accumulation
// (r10 geometry: 64x128 tile, 4x8 micro, grid 512 = 2 blocks/CU), plus a
// register-staged double buffer with ONE barrier per K-step:
//   LOAD(js+1) -> compute buf[cur] -> WRITE buf[cur^1] -> __syncthreads
// Per output: panels of kc=288 over j, sequential fmaf chain (pk), panels
// left-folded into ys at js%9==8 and js==255 -> identical bits to r9/r10.
__global__ __launch_bounds__(256) void k_conv(const float* __restrict__ x,
                                              const float* __restrict__ wT,
                                              const float* __restrict__ cb,
                                              float* __restrict__ y) {
#pragma clang fp contract(off)
    __shared__ __align__(16) float sA[2][KS][MB + 4];   // [buf][kk][m]
    __shared__ __align__(16) float sB[2][KS][NB];       // [buf][kk][o']

    int bm  = blockIdx.x;          // 0..127
    int bn0 = bm << 6;
    int b   = bn0 >> 8;            // single b per tile (64 | 256)
    int n0  = bn0 & 255;
    int o0  = blockIdx.y << 7;     // 0..3

    int tid = threadIdx.x;
    int tm  = tid & 15;            // 4 m-rows each
    int tn  = tid >> 4;            // 8 o-cols each

    float ys[4][8], pk[4][8];
#pragma unroll
    for (int mi = 0; mi < 4; ++mi)
#pragma unroll
        for (int ni = 0; ni < 8; ++ni) { ys[mi][ni] = 0.0f; pk[mi][ni] = 0.0f; }

    const float* xb = x + (size_t)b * SEQ * EMB;

    float4 ra[2], rb[4];

#define LOAD_T(js_)                                                            \
    {                                                                          \
        int k_  = (js_) >> 4;                                                  \
        int i0_ = ((js_) & 15) << 5;                                           \
        _Pragma("unroll")                                                      \
        for (int r = 0; r < 2; ++r) {                                          \
            int q  = tid + (r << 8);                                           \
            int m  = q >> 3;                                                   \
            int c4 = (q & 7) << 2;                                             \
            int s  = ((n0 + m) << 3) - 4 + k_;                                 \
            ra[r] = make_float4(0.f, 0.f, 0.f, 0.f);                           \
            if (s >= 0 && s < SEQ)                                             \
                ra[r] = *(const float4*)(xb + ((size_t)s << 9) + i0_ + c4);    \
        }                                                                      \
        const float* wrow_ = wT + (((size_t)(js_) << 5) << 9) + o0;            \
        _Pragma("unroll")                                                      \
        for (int r = 0; r < 4; ++r) {                                          \
            int q  = tid + (r << 8);                                           \
            int kk = q >> 5;                                                   \
            int o4 = (q & 31) << 2;                                            \
            rb[r] = *(const float4*)(wrow_ + ((size_t)kk << 9) + o4);          \
        }                                                                      \
    }

#define WRITE_T(bf_)                                                           \
    {                                                                          \
        _Pragma("unroll")                                                      \
        for (int r = 0; r < 2; ++r) {                                          \
            int q  = tid + (r << 8);                                           \
            int m  = q >> 3;                                                   \
            int c4 = (q & 7) << 2;                                             \
            sA[bf_][c4 + 0][m] = ra[r].x;                                      \
            sA[bf_][c4 + 1][m] = ra[r].y;                                      \
            sA[bf_][c4 + 2][m] = ra[r].z;                                      \
            sA[bf_][c4 + 3][m] = ra[r].w;                                      \
        }                                                                      \
        _Pragma("unroll")                                                      \
        for (int r = 0; r < 4; ++r) {                                          \
            int q  = tid + (r << 8);                                           \
            int kk = q >> 5;                                                   \
            int o4 = (q & 31) << 2;                                            \
            *(float4*)&sB[bf_][kk][o4] = rb[r];                                \
        }                                                                      \
    }

    // prologue: stage js=0 into buffer 0
    LOAD_T(0);
    WRITE_T(0);
    __syncthreads();

    for (int js = 0; js < 256; ++js) {
        int cur = js & 1;
        if (js < 255) LOAD_T(js + 1);      // global loads in flight during compute

        // micro-kernel: pk chains ascend in kk (exact Eigen panel order)
#pragma unroll
        for (int kk = 0; kk < KS; ++kk) {
            float4 a  = *(const float4*)&sA[cur][kk][tm << 2];
            float4 b0 = *(const float4*)&sB[cur][kk][tn << 3];
            float4 b1 = *(const float4*)&sB[cur][kk][(tn << 3) + 4];
            float av[4] = {a.x, a.y, a.z, a.w};
            float bv[8] = {b0.x, b0.y, b0.z, b0.w, b1.x, b1.y, b1.z, b1.w};
#pragma unroll
            for (int mi = 0; mi < 4; ++mi)
#pragma unroll
                for (int ni = 0; ni < 8; ++ni)
                    pk[mi][ni] = __builtin_fmaf(av[mi], bv[ni], pk[mi][ni]);
        }
        // panel left-fold (ys += pk) at kc=288 boundaries and the 128 tail
        if ((js % 9) == 8 || js == 255) {
#pragma unroll
            for (int mi = 0; mi < 4; ++mi)
#pragma unroll
                for (int ni = 0; ni < 8; ++ni) {
                    ys[mi][ni] = ys[mi][ni] + pk[mi][ni];
                    pk[mi][ni] = 0.0f;
                }
        }
        // write next tile into the buffer nobody reads until after the barrier
        if (js < 255) WRITE_T(cur ^ 1);
        __syncthreads();                   // single barrier per js
    }

    const float* cbp = cb + o0 + (tn << 3);
#pragma unroll
    for (int mi = 0; mi < 4; ++mi) {
        int n = n0 + (tm << 2) + mi;
        float* dst = y + (((size_t)(b << 8) + n) << 9) + o0 + (tn << 3);
#pragma unroll
        for (int ni = 0; ni < 8; ++ni)
            dst[ni] = ys[mi][ni] + cbp[ni];   // bias after full gemm (exact order)
    }
#undef LOAD_T
#undef WRITE_T
}

// K3: per (b,n): off = relu(y) @ lin_w.T + lin_b with Eigen kc=288 panel split
// (512 = 288 + 224), then decode op-for-op in f32 (contract off), XLA tanh,
// jax-f32 linspace t (t = p * f32(1/15)).
__global__ __launch_bounds__(256) void k_decode(const float* __restrict__ y,
                                               const float* __restrict__ lw,
                                               const float* __restrict__ lb,
                                               const float* __restrict__ wb,
                                               int* __restrict__ idx) {
#pragma clang fp contract(off)
    int bn = blockIdx.x * 256 + threadIdx.x;   // 0..8191
    if (bn >= BATCH * NOUT) return;
    const float* yy = y + ((size_t)bn << 9);

    float s0, s1;
    {
        float p0 = 0.0f, p1 = 0.0f;
        for (int e = 0; e < KCL; ++e) {
            float v = yy[e];
            float r = v > 0.0f ? v : 0.0f;
            p0 = __builtin_fmaf(r, lw[e],       p0);
            p1 = __builtin_fmaf(r, lw[EMB + e], p1);
        }
        s0 = p0; s1 = p1;                  // panel 0 stores (beta=0)
    }
    {
        float p0 = 0.0f, p1 = 0.0f;
        for (int e = KCL; e < EMB; ++e) {
            float v = yy[e];
            float r = v > 0.0f ? v : 0.0f;
            p0 = __builtin_fmaf(r, lw[e],       p0);
            p1 = __builtin_fmaf(r, lw[EMB + e], p1);
        }
        s0 = s0 + p0; s1 = s1 + p1;        // panel 1 accumulates
    }
    float off0 = s0 + lb[0];
    float off1 = s1 + lb[1];

    int n = bn & (NOUT - 1);
    float anchor = (0.5f + (float)n) / 256.0f;        // exact in f32
    float dx  = xla_tanhf(off0) * 0.00390625f;        // * poi (2^-8, exact)
    float a1  = off1 + wb[0];
    float tww = xla_tanhf(a1);
    float rwv = tww > 0.0f ? tww : 0.0f;
    float dwv = rwv * 0.00390625f;
    float adx = anchor + dx;                          // left-assoc like jnp
    float x0 = adx - dwv; x0 = x0 < 0.0f ? 0.0f : (x0 > 1.0f ? 1.0f : x0);
    float x1 = adx + dwv; x1 = x1 < 0.0f ? 0.0f : (x1 > 1.0f ? 1.0f : x1);

    const float delta = 1.0f / 15.0f;                 // f32 0.06666667
#pragma unroll
    for (int p = 0; p < PS; ++p) {
        float t  = (float)p * delta;                  // jax linspace: iota*delta, f32
        float om = 1.0f - t;
        float gs = x0 * om + x1 * t;                  // mul,mul,add — contract off
        float gxn = 2.0f * gs - 1.0f;
        float gp1 = gxn + 1.0f;
        float ixx = (gp1 * 2048.0f - 1.0f) * 0.5f;
        float rr = rintf(ixx);                        // round half-even
        int id = (int)rr;
        id = id < 0 ? 0 : (id > SEQ - 1 ? SEQ - 1 : id);
        idx[bn * PS + p] = id;
    }
}

// K4: out[b][n][p][:] = x[b][idx[b,n,p]][:]   (exact f32 row copy, 2048 B)
__global__ __launch_bounds__(128) void k_gather(const float* __restrict__ x,
                                                const int* __restrict__ idx,
                                                float* __restrict__ out) {
    int g = blockIdx.x;                 // (b*256+n)*16+p, 131072 blocks
    int b = g >> 12;
    int sidx = idx[g];
    const float4* src = (const float4*)(x + (((size_t)b * SEQ + sidx) << 9));
    float4* dst = (float4*)(out + ((size_t)g << 9));
    dst[threadIdx.x] = src[threadIdx.x];
}

extern "C" void kernel_launch(void* const* d_in, const int* in_sizes, int n_in,
                              void* d_out, int out_size, void* d_ws, size_t ws_size,
                              hipStream_t stream) {
    const float* x      = (const float*)d_in[0];
    const float* conv_w = (const float*)d_in[1];
    const float* conv_b = (const float*)d_in[2];
    const float* lin_w  = (const float*)d_in[3];
    const float* lin_b  = (const float*)d_in[4];
    const float* wbias  = (const float*)d_in[5];
    float* out = (float*)d_out;

    // Scratch inside d_out (268 MB f32): wT [0,16.8MB), y [16.8,33.6MB).
    // Both consumed by k_decode before k_gather overwrites d_out.
    // idx (512 KB) in d_ws.
    float* wT  = (float*)d_out;
    float* y   = (float*)((char*)d_out + (size_t)16777216);
    int*   idx = (int*)d_ws;

    hipLaunchKernelGGL(k_transpose_w, dim3(16384), dim3(256), 0, stream, conv_w, wT);
    hipLaunchKernelGGL(k_conv,        dim3(128, 4), dim3(256), 0, stream, x, wT, conv_b, y);
    hipLaunchKernelGGL(k_decode,      dim3(32),    dim3(256), 0, stream, y, lin_w, lin_b, wbias, idx);
    hipLaunchKernelGGL(k_gather,      dim3(BATCH * NOUT * PS), dim3(128), 0, stream, x, idx, out);
}

// Round 13
// 1005.891 us; speedup vs baseline: 1.3334x; 1.0760x over previous
//
#include <hip/hip_runtime.h>
#include <cmath>

#define BATCH 32
#define SEQ   2048
#define EMB   512
#define NOUT  256
#define PS    16
#define KW    16
#define JTOT  8192  // K*E flat contraction length, j = k*512 + i (i fastest)
#define KCL   288   // Eigen threaded gebp kc (linear dot: 512 = 288 + 224)

// GEMM tiling for k_conv: M=bn (8192), N=o (512), K=j (8192)
#define MB 64       // bn-tile
#define NB 128      // o-tile
#define KS 32       // j-tile; 288 = 9*KS, tail 128 = 4*KS -> panel folds align

// async global->LDS, 16B per lane, wave-uniform LDS base + lane*16 dest
#define GLDS16(g_, l_) __builtin_amdgcn_global_load_lds(                      \
    (__attribute__((address_space(1))) const void*)(g_),                      \
    (__attribute__((address_space(3))) void*)(l_), 16, 0, 0)

// XLA EmitFastTanh / Eigen ptanh_float: rational approx, f32, FMA Horner.
__device__ __forceinline__ float xla_tanhf(float x) {
#pragma clang fp contract(off)
    float ax = fabsf(x);
    float xc = x;
    if (xc < -7.90531110763549805f) xc = -7.90531110763549805f;
    if (xc >  7.90531110763549805f) xc =  7.90531110763549805f;
    float x2 = xc * xc;
    float p = __builtin_fmaf(x2, -2.76076847742355e-16f, 2.00018790482477e-13f);
    p = __builtin_fmaf(x2, p, -8.60467152213735e-11f);
    p = __builtin_fmaf(x2, p,  5.12229709037114e-08f);
    p = __builtin_fmaf(x2, p,  1.48572235717979e-05f);
    p = __builtin_fmaf(x2, p,  6.37261928875436e-04f);
    p = __builtin_fmaf(x2, p,  4.89352455891786e-03f);
    float num = xc * p;
    float q = __builtin_fmaf(x2, 1.19825839466702e-06f, 1.18534705686654e-04f);
    q = __builtin_fmaf(x2, q, 2.26843463243900e-03f);
    q = __builtin_fmaf(x2, q, 4.89352518554385e-03f);
    float r = num / q;
    return (ax < 0.0004f) ? x : r;
}

// K1: wT[j][o] = conv_w[o][i][k],  j = k*512 + i  (XLA/Eigen im2col order)
__global__ __launch_bounds__(256) void k_transpose_w(const float* __restrict__ w,
                                                     float* __restrict__ wT) {
    int t = blockIdx.x * 256 + threadIdx.x;   // t = j*512 + o
    int o = t & 511;
    int i = (t >> 9) & 511;
    int k = t >> 18;
    wT[t] = w[(size_t)o * 8192 + i * 16 + k];
}

// K2: conv1d as LDS-tiled f32 GEMM, bit-exact Eigen gebp accumulation.
// r10 geometry (64x128 tile, 4x8 micro, 256 thr, grid 512 = 2 blocks/CU) +
// double buffer with ONE barrier per js:
//   STAGE_A(js+1) [reg load->write, regs die immediately]
//   STAGE_B(js+1) [global_load_lds DMA, zero regs]
//   compute buf[cur]  (no live staged regs -> no spill)
//   __syncthreads()   (drains vmcnt incl. DMA, then barrier)
// Per output: panels of kc=288 over j, sequential fmaf chain (pk), panels
// left-folded into ys at js%9==8 and js==255 -> identical bits to r9/r10.
__global__ __launch_bounds__(256) void k_conv(const float* __restrict__ x,
                                              const float* __restrict__ wT,
                                              const float* __restrict__ cb,
                                              float* __restrict__ y) {
#pragma clang fp contract(off)
    __shared__ __align__(16) float sA[2][KS][MB + 4];   // [buf][kk][m]
    __shared__ __align__(16) float sB[2][KS][NB];       // [buf][kk][o'] (lane-linear)

    int bm  = blockIdx.x;          // 0..127
    int bn0 = bm << 6;
    int b   = bn0 >> 8;            // single b per tile (64 | 256)
    int n0  = bn0 & 255;
    int o0  = blockIdx.y << 7;     // 0..3

    int tid  = threadIdx.x;
    int tm   = tid & 15;           // 4 m-rows each
    int tn   = tid >> 4;           // 8 o-cols each
    int lane = tid & 63;
    int wv   = tid >> 6;           // wave id 0..3

    float ys[4][8], pk[4][8];
#pragma unroll
    for (int mi = 0; mi < 4; ++mi)
#pragma unroll
        for (int ni = 0; ni < 8; ++ni) { ys[mi][ni] = 0.0f; pk[mi][ni] = 0.0f; }

    const float* xb = x + (size_t)b * SEQ * EMB;

    // A: 2 float4 per thread, load then write (regs die before compute)
#define STAGE_A(js_, bf_)                                                      \
    {                                                                          \
        int k_  = (js_) >> 4;                                                  \
        int i0_ = ((js_) & 15) << 5;                                           \
        float4 ra0, ra1;                                                       \
        {                                                                      \
            int m  = tid >> 3;                                                 \
            int c4 = (tid & 7) << 2;                                           \
            int s  = ((n0 + m) << 3) - 4 + k_;                                 \
            ra0 = make_float4(0.f, 0.f, 0.f, 0.f);                             \
            if (s >= 0 && s < SEQ)                                             \
                ra0 = *(const float4*)(xb + ((size_t)s << 9) + i0_ + c4);      \
        }                                                                      \
        {                                                                      \
            int q  = tid + 256;                                                \
            int m  = q >> 3;                                                   \
            int c4 = (q & 7) << 2;                                             \
            int s  = ((n0 + m) << 3) - 4 + k_;                                 \
            ra1 = make_float4(0.f, 0.f, 0.f, 0.f);                             \
            if (s >= 0 && s < SEQ)                                             \
                ra1 = *(const float4*)(xb + ((size_t)s << 9) + i0_ + c4);      \
        }                                                                      \
        {                                                                      \
            int m  = tid >> 3;                                                 \
            int c4 = (tid & 7) << 2;                                           \
            sA[bf_][c4 + 0][m] = ra0.x;                                        \
            sA[bf_][c4 + 1][m] = ra0.y;                                        \
            sA[bf_][c4 + 2][m] = ra0.z;                                        \
            sA[bf_][c4 + 3][m] = ra0.w;                                        \
        }                                                                      \
        {                                                                      \
            int q  = tid + 256;                                                \
            int m  = q >> 3;                                                   \
            int c4 = (q & 7) << 2;                                             \
            sA[bf_][c4 + 0][m] = ra1.x;                                        \
            sA[bf_][c4 + 1][m] = ra1.y;                                        \
            sA[bf_][c4 + 2][m] = ra1.z;                                        \
            sA[bf_][c4 + 3][m] = ra1.w;                                        \
        }                                                                      \
    }

    // B: 4 DMA insts per wave; wave wv stages kk rows wv*8..wv*8+7
    // (one inst = 64 lanes x 16B = 2 rows of 512B, lane-linear dest)
#define STAGE_B(js_, bf_)                                                      \
    {                                                                          \
        _Pragma("unroll")                                                      \
        for (int t = 0; t < 4; ++t) {                                          \
            int kkb = (wv << 3) + (t << 1);                                    \
            const float* gsrc = wT + (((size_t)((js_) << 5) + kkb + (lane >> 5)) << 9) \
                                   + o0 + ((lane & 31) << 2);                  \
            GLDS16(gsrc, &sB[bf_][kkb][0]);                                    \
        }                                                                      \
    }

    // prologue: stage js=0 into buffer 0
    STAGE_A(0, 0);
    STAGE_B(0, 0);
    __syncthreads();

    for (int js = 0; js < 256; ++js) {
        int cur = js & 1;
        if (js < 255) {
            STAGE_A(js + 1, cur ^ 1);      // regs die here; vmcnt waits only A
            STAGE_B(js + 1, cur ^ 1);      // async DMA, in flight during compute
        }

        // micro-kernel: pk chains ascend in kk (exact Eigen panel order)
#pragma unroll
        for (int kk = 0; kk < KS; ++kk) {
            float4 a  = *(const float4*)&sA[cur][kk][tm << 2];
            float4 b0 = *(const float4*)&sB[cur][kk][tn << 3];
            float4 b1 = *(const float4*)&sB[cur][kk][(tn << 3) + 4];
            float av[4] = {a.x, a.y, a.z, a.w};
            float bv[8] = {b0.x, b0.y, b0.z, b0.w, b1.x, b1.y, b1.z, b1.w};
#pragma unroll
            for (int mi = 0; mi < 4; ++mi)
#pragma unroll
                for (int ni = 0; ni < 8; ++ni)
                    pk[mi][ni] = __builtin_fmaf(av[mi], bv[ni], pk[mi][ni]);
        }
        // panel left-fold (ys += pk) at kc=288 boundaries and the 128 tail
        if ((js % 9) == 8 || js == 255) {
#pragma unroll
            for (int mi = 0; mi < 4; ++mi)
#pragma unroll
                for (int ni = 0; ni < 8; ++ni) {
                    ys[mi][ni] = ys[mi][ni] + pk[mi][ni];
                    pk[mi][ni] = 0.0f;
                }
        }
        __syncthreads();   // drains vmcnt(0) (incl. DMA) + lgkmcnt, then barrier
    }

    const float* cbp = cb + o0 + (tn << 3);
#pragma unroll
    for (int mi = 0; mi < 4; ++mi) {
        int n = n0 + (tm << 2) + mi;
        float* dst = y + (((size_t)(b << 8) + n) << 9) + o0 + (tn << 3);
#pragma unroll
        for (int ni = 0; ni < 8; ++ni)
            dst[ni] = ys[mi][ni] + cbp[ni];   // bias after full gemm (exact order)
    }
#undef STAGE_A
#undef STAGE_B
}

// K3: per (b,n): off = relu(y) @ lin_w.T + lin_b with Eigen kc=288 panel split
// (512 = 288 + 224), then decode op-for-op in f32 (contract off), XLA tanh,
// jax-f32 linspace t (t = p * f32(1/15)).
__global__ __launch_bounds__(256) void k_decode(const float* __restrict__ y,
                                               const float* __restrict__ lw,
                                               const float* __restrict__ lb,
                                               const float* __restrict__ wb,
                                               int* __restrict__ idx) {
#pragma clang fp contract(off)
    int bn = blockIdx.x * 256 + threadIdx.x;   // 0..8191
    if (bn >= BATCH * NOUT) return;
    const float* yy = y + ((size_t)bn << 9);

    float s0, s1;
    {
        float p0 = 0.0f, p1 = 0.0f;
        for (int e = 0; e < KCL; ++e) {
            float v = yy[e];
            float r = v > 0.0f ? v : 0.0f;
            p0 = __builtin_fmaf(r, lw[e],       p0);
            p1 = __builtin_fmaf(r, lw[EMB + e], p1);
        }
        s0 = p0; s1 = p1;                  // panel 0 stores (beta=0)
    }
    {
        float p0 = 0.0f, p1 = 0.0f;
        for (int e = KCL; e < EMB; ++e) {
            float v = yy[e];
            float r = v > 0.0f ? v : 0.0f;
            p0 = __builtin_fmaf(r, lw[e],       p0);
            p1 = __builtin_fmaf(r, lw[EMB + e], p1);
        }
        s0 = s0 + p0; s1 = s1 + p1;        // panel 1 accumulates
    }
    float off0 = s0 + lb[0];
    float off1 = s1 + lb[1];

    int n = bn & (NOUT - 1);
    float anchor = (0.5f + (float)n) / 256.0f;        // exact in f32
    float dx  = xla_tanhf(off0) * 0.00390625f;        // * poi (2^-8, exact)
    float a1  = off1 + wb[0];
    float tww = xla_tanhf(a1);
    float rwv = tww > 0.0f ? tww : 0.0f;
    float dwv = rwv * 0.00390625f;
    float adx = anchor + dx;                          // left-assoc like jnp
    float x0 = adx - dwv; x0 = x0 < 0.0f ? 0.0f : (x0 > 1.0f ? 1.0f : x0);
    float x1 = adx + dwv; x1 = x1 < 0.0f ? 0.0f : (x1 > 1.0f ? 1.0f : x1);

    const float delta = 1.0f / 15.0f;                 // f32 0.06666667
#pragma unroll
    for (int p = 0; p < PS; ++p) {
        float t  = (float)p * delta;                  // jax linspace: iota*delta, f32
        float om = 1.0f - t;
        float gs = x0 * om + x1 * t;                  // mul,mul,add — contract off
        float gxn = 2.0f * gs - 1.0f;
        float gp1 = gxn + 1.0f;
        float ixx = (gp1 * 2048.0f - 1.0f) * 0.5f;
        float rr = rintf(ixx);                        // round half-even
        int id = (int)rr;
        id = id < 0 ? 0 : (id > SEQ - 1 ? SEQ - 1 : id);
        idx[bn * PS + p] = id;
    }
}

// K4: out[b][n][p][:] = x[b][idx[b,n,p]][:]   (exact f32 row copy, 2048 B)
__global__ __launch_bounds__(128) void k_gather(const float* __restrict__ x,
                                                const int* __restrict__ idx,
                                                float* __restrict__ out) {
    int g = blockIdx.x;                 // (b*256+n)*16+p, 131072 blocks
    int b = g >> 12;
    int sidx = idx[g];
    const float4* src = (const float4*)(x + (((size_t)b * SEQ + sidx) << 9));
    float4* dst = (float4*)(out + ((size_t)g << 9));
    dst[threadIdx.x] = src[threadIdx.x];
}

extern "C" void kernel_launch(void* const* d_in, const int* in_sizes, int n_in,
                              void* d_out, int out_size, void* d_ws, size_t ws_size,
                              hipStream_t stream) {
    const float* x      = (const float*)d_in[0];
    const float* conv_w = (const float*)d_in[1];
    const float* conv_b = (const float*)d_in[2];
    const float* lin_w  = (const float*)d_in[3];
    const float* lin_b  = (const float*)d_in[4];
    const float* wbias  = (const float*)d_in[5];
    float* out = (float*)d_out;

    // Scratch inside d_out (268 MB f32): wT [0,16.8MB), y [16.8,33.6MB).
    // Both consumed by k_decode before k_gather overwrites d_out.
    // idx (512 KB) in d_ws.
    float* wT  = (float*)d_out;
    float* y   = (float*)((char*)d_out + (size_t)16777216);
    int*   idx = (int*)d_ws;

    hipLaunchKernelGGL(k_transpose_w, dim3(16384), dim3(256), 0, stream, conv_w, wT);
    hipLaunchKernelGGL(k_conv,        dim3(128, 4), dim3(256), 0, stream, x, wT, conv_b, y);
    hipLaunchKernelGGL(k_decode,      dim3(32),    dim3(256), 0, stream, y, lin_w, lin_b, wbias, idx);
    hipLaunchKernelGGL(k_gather,      dim3(BATCH * NOUT * PS), dim3(128), 0, stream, x, idx, out);
}